// Round 3
// baseline (999.156 us; speedup 1.0000x reference)
//
#include <hip/hip_runtime.h>

#define TOKENS 4096
#define DIN    4096
#define DOUT   16384

#define BM 256
#define BN 256
#define BK 64
#define NT (DIN / BK)   // 64 k-tiles

#define X_BYTES ((size_t)TOKENS * DIN * 2)   // 32 MB bf16
#define W_BYTES ((size_t)DOUT   * DIN * 2)   // 128 MB bf16

typedef __attribute__((ext_vector_type(8))) short short8;
typedef __attribute__((ext_vector_type(4))) float f32x4;

// fp32 -> bf16 bits, round-to-nearest-even (inputs finite)
__device__ __forceinline__ unsigned short f2bf(float f) {
    unsigned u = __builtin_bit_cast(unsigned, f);
    u += 0x7fffu + ((u >> 16) & 1u);
    return (unsigned short)(u >> 16);
}

#define GLOAD_LDS16(gptr, lptr)                                                        \
    __builtin_amdgcn_global_load_lds(                                                  \
        (const __attribute__((address_space(1))) unsigned int*)(gptr),                 \
        (__attribute__((address_space(3))) unsigned int*)(lptr), 16, 0, 0)

// ---------------- pre-pass converters (memory-bound) ----------------
__global__ __launch_bounds__(256)
void cvt_x_kernel(const float* __restrict__ in, unsigned short* __restrict__ out) {
    const size_t base = ((size_t)blockIdx.x * 256 + threadIdx.x) * 8;
    const float4 a = *(const float4*)&in[base];
    const float4 b = *(const float4*)&in[base + 4];
    uint4 o;
    o.x = (unsigned)f2bf(a.x) | ((unsigned)f2bf(a.y) << 16);
    o.y = (unsigned)f2bf(a.z) | ((unsigned)f2bf(a.w) << 16);
    o.z = (unsigned)f2bf(b.x) | ((unsigned)f2bf(b.y) << 16);
    o.w = (unsigned)f2bf(b.z) | ((unsigned)f2bf(b.w) << 16);
    *(uint4*)&out[base] = o;
}

__global__ __launch_bounds__(256)
void cvt_w_kernel(const int* __restrict__ in, unsigned short* __restrict__ out) {
    const size_t base = ((size_t)blockIdx.x * 256 + threadIdx.x) * 8;
    const int4 a = *(const int4*)&in[base];
    const int4 b = *(const int4*)&in[base + 4];
    uint4 o;   // int8 values are exact in bf16
    o.x = (unsigned)f2bf((float)a.x) | ((unsigned)f2bf((float)a.y) << 16);
    o.y = (unsigned)f2bf((float)a.z) | ((unsigned)f2bf((float)a.w) << 16);
    o.z = (unsigned)f2bf((float)b.x) | ((unsigned)f2bf((float)b.y) << 16);
    o.w = (unsigned)f2bf((float)b.z) | ((unsigned)f2bf((float)b.w) << 16);
    *(uint4*)&out[base] = o;
}

// ---------------- 256x256 bf16 GEMM, minimal-barrier drift schedule ----------------
// 8 waves = 2(M) x 4(N); per-wave output 128x64; BK=64; LDS 2 x (A 32KB + B 32KB).
// LDS linear [buf][A|B][256 rows][8 chunks of 16B]; swizzle on the GLOBAL source:
// phys chunk pc of row r holds global k-chunk gc = pc ^ (r&7); ds_read_b128 of a
// fragment reads chunk (kk*4+quad) ^ (row&7) -> conflict-free.
//
// ROUND-2 LESSON: the 8-barrier/tile phase-locked schedule serializes LDS-read
// bursts against MFMA bursts (both ~2000 cyc/K-tile/CU) -> MfmaUtil capped ~40%.
// This version keeps ONLY the 3 barriers data-correctness requires:
//   bar1: after all waves' B reads drained  -> allows (t+2).B0,B1 stage into cur
//   bar2: after all waves' A reads drained  -> allows (t+2).A0 stage into cur
//   bar3: tile boundary, after counted vmcnt(6) -> publishes tile t+1
// Between barriers the compiler's counted lgkm waits + 2-wave/SIMD drift overlap
// ds_read with MFMA; setprio(1) keeps the MFMA wave favored.
// vmcnt ledger (unchanged, verified): steady-state outstanding after vmcnt(6) =
// (t+2).{B0,B1,A0}; vmcnt(6) at tile t retires exactly tile (t+1)'s 8 loads.
__global__ __launch_bounds__(512, 2)
void gemm_bf16_kernel(const unsigned short* __restrict__ xa,   // [TOKENS][DIN] bf16
                      const unsigned short* __restrict__ wb,   // [DOUT][DIN]  bf16
                      const float* __restrict__ scale,
                      const float* __restrict__ bias,
                      float* __restrict__ out) {
    __shared__ unsigned short smem[2 * 32768];   // 128 KB: [buf][A 16384 | B 16384] shorts

    const int tid  = threadIdx.x;
    const int lane = tid & 63;
    const int wave = tid >> 6;
    const int wm   = wave >> 2;      // 0..1
    const int wn   = wave & 3;       // 0..3
    const int quad = lane >> 4;
    const int l16  = lane & 15;

    // XCD-aware block swizzle (nwg = 1024, divisible by 8 -> bijective)
    const int nwg = (TOKENS / BM) * (DOUT / BN);                       // 16*64 = 1024
    const int wg  = ((int)blockIdx.x & 7) * (nwg >> 3) + ((int)blockIdx.x >> 3);
    const int m0  = (wg & 15) * BM;   // m fastest-varying
    const int n0  = (wg >> 4) * BN;

    // staging: thread handles phys chunks c = i*512+tid of a 128-row half-tile.
    // global source chunk gc = (c&7) ^ (row&7)  (inverse of the read swizzle).
    int gAo[2], gBo[2];
#pragma unroll
    for (int i = 0; i < 2; ++i) {
        const int c  = i * 512 + tid;
        const int r  = c >> 3;             // row within half (0..127)
        const int gc = (c & 7) ^ (r & 7);
        gAo[i] = (m0 + r) * DIN + gc * 8;  // bf16 elem offset (h,k added at stage)
        gBo[i] = (n0 + r) * DIN + gc * 8;
    }

#define STAGE(b, isA, h, kt)                                                             \
    do {                                                                                 \
        const unsigned short* _s = (isA) ? xa : wb;                                      \
        const int _g0 = ((isA) ? gAo[0] : gBo[0]) + (h) * 128 * DIN + (kt) * BK;         \
        const int _g1 = ((isA) ? gAo[1] : gBo[1]) + (h) * 128 * DIN + (kt) * BK;         \
        unsigned short* _d =                                                             \
            &smem[(b) * 32768 + ((isA) ? 0 : 16384) + ((h) * 1024 + wave * 64) * 8];     \
        GLOAD_LDS16(_s + _g0, _d);                                                       \
        GLOAD_LDS16(_s + _g1, _d + 4096);                                                \
    } while (0)

    // fragment ds_read offsets (shorts): row = base + l16, chunk = (kk*4+quad)^(row&7)
    const int s7    = l16 & 7;
    const int cx0   = (quad ^ s7) * 8;
    const int cx1   = ((quad ^ s7) ^ 4) * 8;
    const int aoff0 = (wm * 128 + l16) * 64 + cx0;
    const int aoff1 = (wm * 128 + l16) * 64 + cx1;
    const int boff0 = (wn * 64 + l16) * 64 + cx0;
    const int boff1 = (wn * 64 + l16) * 64 + cx1;

#define READ_A(mh)                                                                       \
    do {                                                                                 \
        _Pragma("unroll") for (int i = 0; i < 4; ++i) {                                  \
            af[i * 2]     = *(const short8*)&pA[aoff0 + (mh) * 4096 + i * 1024];         \
            af[i * 2 + 1] = *(const short8*)&pA[aoff1 + (mh) * 4096 + i * 1024];         \
        }                                                                                \
    } while (0)

#define READ_B(dst, nh)                                                                  \
    do {                                                                                 \
        _Pragma("unroll") for (int j = 0; j < 2; ++j) {                                  \
            dst[j * 2]     = *(const short8*)&pB[boff0 + (nh) * 2048 + j * 1024];        \
            dst[j * 2 + 1] = *(const short8*)&pB[boff1 + (nh) * 2048 + j * 1024];        \
        }                                                                                \
    } while (0)

// k-outer: 8 independent MFMAs between dependent writes to the same acc
#define MFMA_Q(mh, nh, bv)                                                               \
    do {                                                                                 \
        __builtin_amdgcn_s_setprio(1);                                                   \
        _Pragma("unroll") for (int k = 0; k < 2; ++k)                                    \
            _Pragma("unroll") for (int i = 0; i < 4; ++i)                                \
                _Pragma("unroll") for (int j = 0; j < 2; ++j)                            \
                    acc[(mh) * 4 + i][(nh) * 2 + j] =                                    \
                        __builtin_amdgcn_mfma_f32_16x16x32_bf16(                         \
                            af[i * 2 + k], bv[j * 2 + k],                                \
                            acc[(mh) * 4 + i][(nh) * 2 + j], 0, 0, 0);                   \
        __builtin_amdgcn_s_setprio(0);                                                   \
    } while (0)

    // ---- prologue: tile0 fully + tile1 {B0,B1,A0}; wait tile0 (6 stay in flight) ----
    STAGE(0, 1, 0, 0);   // t0.A0
    STAGE(0, 0, 0, 0);   // t0.B0
    STAGE(0, 0, 1, 0);   // t0.B1
    STAGE(0, 1, 1, 0);   // t0.A1
    STAGE(1, 0, 0, 1);   // t1.B0
    STAGE(1, 0, 1, 1);   // t1.B1
    STAGE(1, 1, 0, 1);   // t1.A0

    f32x4 acc[8][4];
#pragma unroll
    for (int i = 0; i < 8; ++i)
#pragma unroll
        for (int j = 0; j < 4; ++j)
            acc[i][j] = (f32x4){0.f, 0.f, 0.f, 0.f};

    asm volatile("s_waitcnt vmcnt(6)" ::: "memory");
    __builtin_amdgcn_s_barrier();

#pragma unroll 2
    for (int t = 0; t < NT; ++t) {
        const int cur = t & 1;
        const unsigned short* pA = &smem[cur * 32768];
        const unsigned short* pB = pA + 16384;
        short8 af[8], bq0[4], bq1[4];

        // ---- chunk 1: A0+B0 reads; stage (t+1).A1 -> other buf; MFMA (0,0) ----
        READ_A(0);
        READ_B(bq0, 0);
        if (t + 1 < NT) STAGE(cur ^ 1, 1, 1, t + 1);
        MFMA_Q(0, 0, bq0);

        // ---- chunk 2: B1 reads (hoistable above MFMA(0,0)); MFMA (0,1) ----
        READ_B(bq1, 1);
        MFMA_Q(0, 1, bq1);
        asm volatile("s_waitcnt lgkmcnt(0)" ::: "memory");   // wave's B reads drained
        __builtin_amdgcn_s_barrier();                        // bar1: all waves' B reads done

        // ---- chunk 3: A1 reads; stage (t+2).B0,B1 -> cur (B regions free); MFMA (1,1) ----
        READ_A(1);
        if (t + 2 < NT) {
            STAGE(cur, 0, 0, t + 2);
            STAGE(cur, 0, 1, t + 2);
        }
        MFMA_Q(1, 1, bq1);
        asm volatile("s_waitcnt lgkmcnt(0)" ::: "memory");   // wave's A reads drained
        __builtin_amdgcn_s_barrier();                        // bar2: all waves' A reads done

        // ---- chunk 4: stage (t+2).A0 -> cur (A regions free); MFMA (1,0); publish ----
        if (t + 2 < NT) STAGE(cur, 1, 0, t + 2);
        MFMA_Q(1, 0, bq0);
        if (t < NT - 2) {
            asm volatile("s_waitcnt vmcnt(6)" ::: "memory");  // retires tile (t+1)'s 8 loads
        } else if (t == NT - 2) {
            asm volatile("s_waitcnt vmcnt(0)" ::: "memory");
        }
        __builtin_amdgcn_s_barrier();                        // bar3: tile boundary, publish
    }

#undef STAGE
#undef READ_A
#undef READ_B
#undef MFMA_Q

    // ---- epilogue: C/D col=l16 (n), row=quad*4+r (m); fuse scale+bias ----
#pragma unroll
    for (int aj = 0; aj < 4; ++aj) {
        const int col = n0 + wn * 64 + aj * 16 + l16;
        const float s = scale[col];
        const float b = bias[col];
#pragma unroll
        for (int ai = 0; ai < 8; ++ai) {
            const int row0 = m0 + wm * 128 + ai * 16 + quad * 4;
#pragma unroll
            for (int r = 0; r < 4; ++r)
                out[(size_t)(row0 + r) * DOUT + col] = acc[ai][aj][r] * s + b;
        }
    }
}

// ---------------- fallback (round-1 kernel, used only if ws too small) ----------------
#define FBM 128
#define FBN 128
#define FBK 32
#define LDSS 40
__global__ __launch_bounds__(256, 2)
void gemm_fallback_kernel(const float* __restrict__ x, const int* __restrict__ qw,
                          const float* __restrict__ scale, const float* __restrict__ bias,
                          float* __restrict__ out) {
    __shared__ unsigned short As[FBM * LDSS];
    __shared__ unsigned short Bs[FBN * LDSS];
    const int tid = threadIdx.x, lane = tid & 63, wave = tid >> 6;
    const int wm = wave >> 1, wn = wave & 1, quad = lane >> 4, l16 = lane & 15;
    const int m0 = blockIdx.x * FBM, n0 = blockIdx.y * FBN;
    const int srow = tid >> 3, scol = (tid & 7) * 4;
    f32x4 acc[4][4];
#pragma unroll
    for (int i = 0; i < 4; ++i)
#pragma unroll
        for (int j = 0; j < 4; ++j) acc[i][j] = (f32x4){0.f, 0.f, 0.f, 0.f};
    for (int k0 = 0; k0 < DIN; k0 += FBK) {
        __syncthreads();
#pragma unroll
        for (int p = 0; p < 4; ++p) {
            const int r = p * 32 + srow;
            const float4 v = *(const float4*)&x[(size_t)(m0 + r) * DIN + k0 + scol];
            const unsigned a01 = (unsigned)f2bf(v.x) | ((unsigned)f2bf(v.y) << 16);
            const unsigned a23 = (unsigned)f2bf(v.z) | ((unsigned)f2bf(v.w) << 16);
            *(unsigned long long*)&As[r * LDSS + scol] =
                (unsigned long long)a01 | ((unsigned long long)a23 << 32);
        }
#pragma unroll
        for (int p = 0; p < 4; ++p) {
            const int r = p * 32 + srow;
            const int4 v = *(const int4*)&qw[(size_t)(n0 + r) * DIN + k0 + scol];
            const unsigned b01 = (unsigned)f2bf((float)v.x) | ((unsigned)f2bf((float)v.y) << 16);
            const unsigned b23 = (unsigned)f2bf((float)v.z) | ((unsigned)f2bf((float)v.w) << 16);
            *(unsigned long long*)&Bs[r * LDSS + scol] =
                (unsigned long long)b01 | ((unsigned long long)b23 << 32);
        }
        __syncthreads();
        short8 af[4], bfv[4];
#pragma unroll
        for (int i = 0; i < 4; ++i)
            af[i] = *(const short8*)&As[(wm * 64 + i * 16 + l16) * LDSS + quad * 8];
#pragma unroll
        for (int j = 0; j < 4; ++j)
            bfv[j] = *(const short8*)&Bs[(wn * 64 + j * 16 + l16) * LDSS + quad * 8];
#pragma unroll
        for (int i = 0; i < 4; ++i)
#pragma unroll
            for (int j = 0; j < 4; ++j)
                acc[i][j] = __builtin_amdgcn_mfma_f32_16x16x32_bf16(af[i], bfv[j], acc[i][j], 0, 0, 0);
    }
#pragma unroll
    for (int j = 0; j < 4; ++j) {
        const int col = n0 + wn * 64 + j * 16 + l16;
        const float s = scale[col], b = bias[col];
#pragma unroll
        for (int i = 0; i < 4; ++i) {
            const int row0 = m0 + wm * 64 + i * 16 + quad * 4;
#pragma unroll
            for (int r = 0; r < 4; ++r)
                out[(size_t)(row0 + r) * DOUT + col] = acc[i][j][r] * s + b;
        }
    }
}

extern "C" void kernel_launch(void* const* d_in, const int* in_sizes, int n_in,
                              void* d_out, int out_size, void* d_ws, size_t ws_size,
                              hipStream_t stream) {
    const float* x     = (const float*)d_in[0];
    const int*   qw    = (const int*)d_in[1];
    const float* scale = (const float*)d_in[2];
    const float* bias  = (const float*)d_in[3];
    float*       out   = (float*)d_out;

    if (ws_size >= X_BYTES + W_BYTES) {
        unsigned short* x_bf = (unsigned short*)d_ws;
        unsigned short* w_bf = (unsigned short*)((char*)d_ws + X_BYTES);
        cvt_x_kernel<<<dim3((TOKENS * DIN) / (256 * 8)), dim3(256), 0, stream>>>(x, x_bf);
        cvt_w_kernel<<<dim3((DOUT * DIN) / (256 * 8)), dim3(256), 0, stream>>>(qw, w_bf);
        gemm_bf16_kernel<<<dim3((TOKENS / BM) * (DOUT / BN)), dim3(512), 0, stream>>>(
            x_bf, w_bf, scale, bias, out);
    } else {
        gemm_fallback_kernel<<<dim3(TOKENS / FBM, DOUT / FBN), dim3(256), 0, stream>>>(
            x, qw, scale, bias, out);
    }
}

// Round 4
// 970.901 us; speedup vs baseline: 1.0291x; 1.0291x over previous
//
#include <hip/hip_runtime.h>

#define TOKENS 4096
#define DIN    4096
#define DOUT   16384

#define BM 256
#define BN 256
#define BK 64
#define NT (DIN / BK)   // 64 k-tiles

#define X_BYTES ((size_t)TOKENS * DIN * 2)   // 32 MB bf16
#define W_BYTES ((size_t)DOUT   * DIN * 2)   // 128 MB bf16

typedef __attribute__((ext_vector_type(8))) short short8;
typedef __attribute__((ext_vector_type(4))) float f32x4;

// fp32 -> bf16 bits, round-to-nearest-even (inputs finite)
__device__ __forceinline__ unsigned short f2bf(float f) {
    unsigned u = __builtin_bit_cast(unsigned, f);
    u += 0x7fffu + ((u >> 16) & 1u);
    return (unsigned short)(u >> 16);
}

#define GLOAD_LDS16(gptr, lptr)                                                        \
    __builtin_amdgcn_global_load_lds(                                                  \
        (const __attribute__((address_space(1))) unsigned int*)(gptr),                 \
        (__attribute__((address_space(3))) unsigned int*)(lptr), 16, 0, 0)

// ---------------- pre-pass converters (memory-bound) ----------------
__global__ __launch_bounds__(256)
void cvt_x_kernel(const float* __restrict__ in, unsigned short* __restrict__ out) {
    const size_t base = ((size_t)blockIdx.x * 256 + threadIdx.x) * 8;
    const float4 a = *(const float4*)&in[base];
    const float4 b = *(const float4*)&in[base + 4];
    uint4 o;
    o.x = (unsigned)f2bf(a.x) | ((unsigned)f2bf(a.y) << 16);
    o.y = (unsigned)f2bf(a.z) | ((unsigned)f2bf(a.w) << 16);
    o.z = (unsigned)f2bf(b.x) | ((unsigned)f2bf(b.y) << 16);
    o.w = (unsigned)f2bf(b.z) | ((unsigned)f2bf(b.w) << 16);
    *(uint4*)&out[base] = o;
}

__global__ __launch_bounds__(256)
void cvt_w_kernel(const int* __restrict__ in, unsigned short* __restrict__ out) {
    const size_t base = ((size_t)blockIdx.x * 256 + threadIdx.x) * 8;
    const int4 a = *(const int4*)&in[base];
    const int4 b = *(const int4*)&in[base + 4];
    uint4 o;   // int8 values are exact in bf16
    o.x = (unsigned)f2bf((float)a.x) | ((unsigned)f2bf((float)a.y) << 16);
    o.y = (unsigned)f2bf((float)a.z) | ((unsigned)f2bf((float)a.w) << 16);
    o.z = (unsigned)f2bf((float)b.x) | ((unsigned)f2bf((float)b.y) << 16);
    o.w = (unsigned)f2bf((float)b.z) | ((unsigned)f2bf((float)b.w) << 16);
    *(uint4*)&out[base] = o;
}

// ---------------- 256x256 bf16 GEMM, fence-free double-buffer ----------------
// 8 waves = 2(M) x 4(N); per-wave output 128x64; BK=64; LDS 2 x (A 32KB + B 32KB).
// LDS linear [buf][A|B][256 rows][8 chunks of 16B]; swizzle on the GLOBAL source:
// phys chunk pc of row r holds global k-chunk gc = pc ^ (r&7); ds_read_b128 of a
// fragment reads chunk (kk*4+quad) ^ (row&7) -> 2 lanes/bank, conflict-free.
//
// ROUND-3 LESSON (counters): with stages into the LIVE buffer, the required lgkm
// fences chop the tile into regions; all waves burst reads then burst MFMAs ->
// LDS (~2600cy) and MFMA (~2480cy) SERIALIZE (40% util + 45% stall). Fix: stage
// the WHOLE tile t+1 into buf^1 at the TOP of tile t (classic dbuf, no live-buffer
// writes -> no intra-tile fences at all). Interior is one scheduling region,
// hand-pipelined at 8-MFMA granularity: each sub-phase issues the NEXT sub-phase's
// fragment reads before its MFMA cluster (boustrophedon k0:q00,q01,q11,q10 then
// k1 reversed; per-acc k-order unchanged -> bit-identical output). Tile end:
// lgkmcnt(0) (free, reads already consumed) + vmcnt(0) (loads issued ~3000cy
// earlier -> near-instant) + one barrier.
__global__ __launch_bounds__(512, 2)
void gemm_bf16_kernel(const unsigned short* __restrict__ xa,   // [TOKENS][DIN] bf16
                      const unsigned short* __restrict__ wb,   // [DOUT][DIN]  bf16
                      const float* __restrict__ scale,
                      const float* __restrict__ bias,
                      float* __restrict__ out) {
    __shared__ unsigned short smem[2 * 32768];   // 128 KB: [buf][A 16384 | B 16384] shorts

    const int tid  = threadIdx.x;
    const int lane = tid & 63;
    const int wave = tid >> 6;
    const int wm   = wave >> 2;      // 0..1
    const int wn   = wave & 3;       // 0..3
    const int quad = lane >> 4;
    const int l16  = lane & 15;

    // XCD-aware block swizzle (nwg = 1024, divisible by 8 -> bijective)
    const int nwg = (TOKENS / BM) * (DOUT / BN);                       // 16*64 = 1024
    const int wg  = ((int)blockIdx.x & 7) * (nwg >> 3) + ((int)blockIdx.x >> 3);
    const int m0  = (wg & 15) * BM;   // m fastest-varying
    const int n0  = (wg >> 4) * BN;

    // staging: thread handles phys chunks c = i*512+tid of a 128-row half-tile.
    // global source chunk gc = (c&7) ^ (row&7)  (inverse of the read swizzle).
    int gAo[2], gBo[2];
#pragma unroll
    for (int i = 0; i < 2; ++i) {
        const int c  = i * 512 + tid;
        const int r  = c >> 3;             // row within half (0..127)
        const int gc = (c & 7) ^ (r & 7);
        gAo[i] = (m0 + r) * DIN + gc * 8;  // bf16 elem offset (h,k added at stage)
        gBo[i] = (n0 + r) * DIN + gc * 8;
    }

#define STAGE(b, isA, h, kt)                                                             \
    do {                                                                                 \
        const unsigned short* _s = (isA) ? xa : wb;                                      \
        const int _g0 = ((isA) ? gAo[0] : gBo[0]) + (h) * 128 * DIN + (kt) * BK;         \
        const int _g1 = ((isA) ? gAo[1] : gBo[1]) + (h) * 128 * DIN + (kt) * BK;         \
        unsigned short* _d =                                                             \
            &smem[(b) * 32768 + ((isA) ? 0 : 16384) + ((h) * 1024 + wave * 64) * 8];     \
        GLOAD_LDS16(_s + _g0, _d);                                                       \
        GLOAD_LDS16(_s + _g1, _d + 4096);                                                \
    } while (0)

    // fragment ds_read offsets (shorts): row = base + l16, chunk = (kk*4+quad)^(row&7)
    const int s7    = l16 & 7;
    const int cx0   = (quad ^ s7) * 8;
    const int cx1   = ((quad ^ s7) ^ 4) * 8;
    const int aoff0 = (wm * 128 + l16) * 64 + cx0;   // k-half 0
    const int aoff1 = (wm * 128 + l16) * 64 + cx1;   // k-half 1
    const int boff0 = (wn * 64 + l16) * 64 + cx0;
    const int boff1 = (wn * 64 + l16) * 64 + cx1;

#define RD_A(dst, kf, mh)                                                                \
    do {                                                                                 \
        _Pragma("unroll") for (int i = 0; i < 4; ++i)                                    \
            dst[i] = *(const short8*)&pA[((kf) ? aoff1 : aoff0) + (mh) * 4096 + i * 1024]; \
    } while (0)

#define RD_B(dst, kf, nh)                                                                \
    do {                                                                                 \
        _Pragma("unroll") for (int j = 0; j < 2; ++j)                                    \
            dst[j] = *(const short8*)&pB[((kf) ? boff1 : boff0) + (nh) * 2048 + j * 1024]; \
    } while (0)

// 8 MFMAs: one quadrant x one k-half
#define MM8(aV, bV, mh, nh)                                                              \
    do {                                                                                 \
        __builtin_amdgcn_s_setprio(1);                                                   \
        _Pragma("unroll") for (int i = 0; i < 4; ++i)                                    \
            _Pragma("unroll") for (int j = 0; j < 2; ++j)                                \
                acc[(mh) * 4 + i][(nh) * 2 + j] = __builtin_amdgcn_mfma_f32_16x16x32_bf16( \
                    aV[i], bV[j], acc[(mh) * 4 + i][(nh) * 2 + j], 0, 0, 0);             \
        __builtin_amdgcn_s_setprio(0);                                                   \
    } while (0)

    // ---- prologue: stage tile0 into buf0, drain, publish ----
    STAGE(0, 1, 0, 0);
    STAGE(0, 1, 1, 0);
    STAGE(0, 0, 0, 0);
    STAGE(0, 0, 1, 0);

    f32x4 acc[8][4];
#pragma unroll
    for (int i = 0; i < 8; ++i)
#pragma unroll
        for (int j = 0; j < 4; ++j)
            acc[i][j] = (f32x4){0.f, 0.f, 0.f, 0.f};

    asm volatile("s_waitcnt vmcnt(0)" ::: "memory");
    __builtin_amdgcn_s_barrier();

#pragma unroll 2
    for (int t = 0; t < NT; ++t) {
        const int cur = t & 1;
        const unsigned short* pA = &smem[cur * 32768];
        const unsigned short* pB = pA + 16384;

        // top-loaded prefetch: whole tile t+1 into the OTHER buffer (no reader)
        if (t + 1 < NT) {
            STAGE(cur ^ 1, 1, 0, t + 1);
            STAGE(cur ^ 1, 1, 1, t + 1);
            STAGE(cur ^ 1, 0, 0, t + 1);
            STAGE(cur ^ 1, 0, 1, t + 1);
        }

        short8 a0k0[4], a1k0[4], a1k1[4], a0k1[4];
        short8 b0k0[2], b1k0[2], b0k1[2], b1k1[2];

        RD_A(a0k0, 0, 0);            // s1 operands
        RD_B(b0k0, 0, 0);
        RD_B(b1k0, 0, 1);            // prefetch s2
        MM8(a0k0, b0k0, 0, 0);       // s1: q00,k0
        RD_A(a1k0, 0, 1);            // prefetch s3
        MM8(a0k0, b1k0, 0, 1);       // s2: q01,k0
        RD_B(b0k1, 1, 0);            // prefetch s5 (part)
        MM8(a1k0, b1k0, 1, 1);       // s3: q11,k0
        RD_A(a1k1, 1, 1);            // prefetch s5
        MM8(a1k0, b0k0, 1, 0);       // s4: q10,k0
        RD_B(b1k1, 1, 1);            // prefetch s6
        MM8(a1k1, b0k1, 1, 0);       // s5: q10,k1
        RD_A(a0k1, 1, 0);            // prefetch s7
        MM8(a1k1, b1k1, 1, 1);       // s6: q11,k1
        MM8(a0k1, b1k1, 0, 1);       // s7: q01,k1
        MM8(a0k1, b0k1, 0, 0);       // s8: q00,k1

        // tile boundary: lgkm drain is free (reads consumed); vmcnt(0) near-free
        // (loads issued at tile top, ~3000cy ago); then publish tile t+1.
        asm volatile("s_waitcnt vmcnt(0) lgkmcnt(0)" ::: "memory");
        __builtin_amdgcn_s_barrier();
    }

#undef STAGE
#undef RD_A
#undef RD_B
#undef MM8

    // ---- epilogue: C/D col=l16 (n), row=quad*4+r (m); fuse scale+bias ----
#pragma unroll
    for (int aj = 0; aj < 4; ++aj) {
        const int col = n0 + wn * 64 + aj * 16 + l16;
        const float s = scale[col];
        const float b = bias[col];
#pragma unroll
        for (int ai = 0; ai < 8; ++ai) {
            const int row0 = m0 + wm * 128 + ai * 16 + quad * 4;
#pragma unroll
            for (int r = 0; r < 4; ++r)
                out[(size_t)(row0 + r) * DOUT + col] = acc[ai][aj][r] * s + b;
        }
    }
}

// ---------------- fallback (round-1 kernel, used only if ws too small) ----------------
#define FBM 128
#define FBN 128
#define FBK 32
#define LDSS 40
__global__ __launch_bounds__(256, 2)
void gemm_fallback_kernel(const float* __restrict__ x, const int* __restrict__ qw,
                          const float* __restrict__ scale, const float* __restrict__ bias,
                          float* __restrict__ out) {
    __shared__ unsigned short As[FBM * LDSS];
    __shared__ unsigned short Bs[FBN * LDSS];
    const int tid = threadIdx.x, lane = tid & 63, wave = tid >> 6;
    const int wm = wave >> 1, wn = wave & 1, quad = lane >> 4, l16 = lane & 15;
    const int m0 = blockIdx.x * FBM, n0 = blockIdx.y * FBN;
    const int srow = tid >> 3, scol = (tid & 7) * 4;
    f32x4 acc[4][4];
#pragma unroll
    for (int i = 0; i < 4; ++i)
#pragma unroll
        for (int j = 0; j < 4; ++j) acc[i][j] = (f32x4){0.f, 0.f, 0.f, 0.f};
    for (int k0 = 0; k0 < DIN; k0 += FBK) {
        __syncthreads();
#pragma unroll
        for (int p = 0; p < 4; ++p) {
            const int r = p * 32 + srow;
            const float4 v = *(const float4*)&x[(size_t)(m0 + r) * DIN + k0 + scol];
            const unsigned a01 = (unsigned)f2bf(v.x) | ((unsigned)f2bf(v.y) << 16);
            const unsigned a23 = (unsigned)f2bf(v.z) | ((unsigned)f2bf(v.w) << 16);
            *(unsigned long long*)&As[r * LDSS + scol] =
                (unsigned long long)a01 | ((unsigned long long)a23 << 32);
        }
#pragma unroll
        for (int p = 0; p < 4; ++p) {
            const int r = p * 32 + srow;
            const int4 v = *(const int4*)&qw[(size_t)(n0 + r) * DIN + k0 + scol];
            const unsigned b01 = (unsigned)f2bf((float)v.x) | ((unsigned)f2bf((float)v.y) << 16);
            const unsigned b23 = (unsigned)f2bf((float)v.z) | ((unsigned)f2bf((float)v.w) << 16);
            *(unsigned long long*)&Bs[r * LDSS + scol] =
                (unsigned long long)b01 | ((unsigned long long)b23 << 32);
        }
        __syncthreads();
        short8 af[4], bfv[4];
#pragma unroll
        for (int i = 0; i < 4; ++i)
            af[i] = *(const short8*)&As[(wm * 64 + i * 16 + l16) * LDSS + quad * 8];
#pragma unroll
        for (int j = 0; j < 4; ++j)
            bfv[j] = *(const short8*)&Bs[(wn * 64 + j * 16 + l16) * LDSS + quad * 8];
#pragma unroll
        for (int i = 0; i < 4; ++i)
#pragma unroll
            for (int j = 0; j < 4; ++j)
                acc[i][j] = __builtin_amdgcn_mfma_f32_16x16x32_bf16(af[i], bfv[j], acc[i][j], 0, 0, 0);
    }
#pragma unroll
    for (int j = 0; j < 4; ++j) {
        const int col = n0 + wn * 64 + j * 16 + l16;
        const float s = scale[col], b = bias[col];
#pragma unroll
        for (int i = 0; i < 4; ++i) {
            const int row0 = m0 + wm * 64 + i * 16 + quad * 4;
#pragma unroll
            for (int r = 0; r < 4; ++r)
                out[(size_t)(row0 + r) * DOUT + col] = acc[i][j][r] * s + b;
        }
    }
}

extern "C" void kernel_launch(void* const* d_in, const int* in_sizes, int n_in,
                              void* d_out, int out_size, void* d_ws, size_t ws_size,
                              hipStream_t stream) {
    const float* x     = (const float*)d_in[0];
    const int*   qw    = (const int*)d_in[1];
    const float* scale = (const float*)d_in[2];
    const float* bias  = (const float*)d_in[3];
    float*       out   = (float*)d_out;

    if (ws_size >= X_BYTES + W_BYTES) {
        unsigned short* x_bf = (unsigned short*)d_ws;
        unsigned short* w_bf = (unsigned short*)((char*)d_ws + X_BYTES);
        cvt_x_kernel<<<dim3((TOKENS * DIN) / (256 * 8)), dim3(256), 0, stream>>>(x, x_bf);
        cvt_w_kernel<<<dim3((DOUT * DIN) / (256 * 8)), dim3(256), 0, stream>>>(qw, w_bf);
        gemm_bf16_kernel<<<dim3((TOKENS / BM) * (DOUT / BN)), dim3(512), 0, stream>>>(
            x_bf, w_bf, scale, bias, out);
    } else {
        gemm_fallback_kernel<<<dim3(TOKENS / FBM, DOUT / FBN), dim3(256), 0, stream>>>(
            x, qw, scale, bias, out);
    }
}